// Round 9
// baseline (177.425 us; speedup 1.0000x reference)
//
#include <hip/hip_runtime.h>
#include <hip/hip_bf16.h>
#include <cstdint>
#include <cstddef>

#define DEVI __device__ __forceinline__

typedef __attribute__((ext_vector_type(8))) __bf16 bf16x8;
typedef __attribute__((ext_vector_type(4))) float  f32x4;
typedef __attribute__((ext_vector_type(4))) unsigned int uint4v;
typedef __attribute__((ext_vector_type(2))) unsigned int uint2v;

static constexpr int D_EMB = 1024;
static constexpr int NH    = 16;
static constexpr int HDIM  = 64;
static constexpr int BATCH = 2;
static constexpr int SEQ   = 2048;
static constexpr int MTOK  = BATCH * SEQ;    // 4096
static constexpr int NQKV  = 3 * D_EMB;      // 3072
static constexpr float L2E = 1.44269504088896340736f;
static constexpr float CSCALE = 0.125f * L2E;   // 1/sqrt(64) * log2(e), folded into Q

#if __has_builtin(__builtin_amdgcn_exp2f)
#define EXP2F(x) __builtin_amdgcn_exp2f(x)
#else
#define EXP2F(x) exp2f(x)
#endif

typedef __attribute__((address_space(1))) unsigned int* gas_u32;
typedef __attribute__((address_space(3))) unsigned int* las_u32;

// async global->LDS, 16B per lane; dest must be linear (wave base + lane*16)
DEVI void gl_lds16(const void* g, void* l) {
  __builtin_amdgcn_global_load_lds((gas_u32)(void*)g, (las_u32)l, 16, 0, 0);
}

DEVI unsigned pack2bf(float lo, float hi) {
  unsigned short a = __builtin_bit_cast(unsigned short, (__bf16)lo);
  unsigned short b = __builtin_bit_cast(unsigned short, (__bf16)hi);
  return (unsigned)a | ((unsigned)b << 16);
}

// ---------------- fused cast: x + all 4 weights in ONE launch ----------------
__global__ __launch_bounds__(256) void cast_all(const float* __restrict__ x,
                                                const float* __restrict__ Wq,
                                                const float* __restrict__ Wk,
                                                const float* __restrict__ Wv,
                                                const float* __restrict__ Wo,
                                                __bf16* __restrict__ xb,
                                                __bf16* __restrict__ Wcat,
                                                __bf16* __restrict__ Wob) {
  const int bid = blockIdx.x;
  const float* src;
  __bf16* dst;
  size_t off;
  if (bid < 2048)      { src = x;  dst = xb;   off = (size_t)bid * 2048; }
  else if (bid < 2560) { src = Wq; dst = Wcat; off = (size_t)(bid - 2048) * 2048; }
  else if (bid < 3072) { src = Wk; dst = Wcat + (1u << 20); off = (size_t)(bid - 2560) * 2048; }
  else if (bid < 3584) { src = Wv; dst = Wcat + (2u << 20); off = (size_t)(bid - 3072) * 2048; }
  else                 { src = Wo; dst = Wob;  off = (size_t)(bid - 3584) * 2048; }
  size_t i = off + (size_t)threadIdx.x * 8;
  const f32x4* p = (const f32x4*)(src + i);
  f32x4 a = p[0], b = p[1];
  bf16x8 o;
  o[0] = (__bf16)a[0]; o[1] = (__bf16)a[1]; o[2] = (__bf16)a[2]; o[3] = (__bf16)a[3];
  o[4] = (__bf16)b[0]; o[5] = (__bf16)b[1]; o[6] = (__bf16)b[2]; o[7] = (__bf16)b[3];
  *(bf16x8*)(dst + i) = o;
}

// ---------------- GEMM: C(M,N) = A(M,K) * B(N,K)^T + bias ----------------
// R5-proven structure: tile BMx128, BK=64, 256 threads (4 waves 2x2), wave
// tile (BM/2)x64. LDS [row][64] bf16 (128B rows), XOR swizzle chunk^=row&7.
// bias select: col<1024->b0,<2048->b1,else b2. qscale multiplies cols<1024.
// VFOLD: cols >= 2048 (V projection) written TRANSPOSED into Vt(B,H,Hd,N).
template <typename OutT, int BM, bool VFOLD>
__global__ __launch_bounds__(256) void gemm_bt(const __bf16* __restrict__ A,
                                               const __bf16* __restrict__ B,
                                               const float* __restrict__ b0,
                                               const float* __restrict__ b1,
                                               const float* __restrict__ b2,
                                               float qscale,
                                               OutT* __restrict__ C,
                                               __bf16* __restrict__ Vt,
                                               int K, int lda, int ldb, int ldc) {
  constexpr int ACH = BM / 32;
  constexpr int MR  = BM / 32;
  __shared__ __align__(16) unsigned char lds[BM * 128 + 16384];
  unsigned char* As = lds;
  unsigned char* Bs = lds + BM * 128;
  const int t = threadIdx.x;
  const int lane = t & 63;
  const int w = t >> 6;
  const int c = lane & 15, g = lane >> 4;
  const int wr = w >> 1, wc = w & 1;
  const int brow = blockIdx.y * BM;
  const int bcol = blockIdx.x * 128;

  f32x4 acc[MR][4] = {};

  int rs[4], chs[4];
#pragma unroll
  for (int i = 0; i < 4; i++) {
    int lb = i * 4096 + t * 16;
    int row = lb >> 7, ch = (lb & 127) >> 4;
    rs[i] = row; chs[i] = ch ^ (row & 7);
  }

  for (int k0 = 0; k0 < K; k0 += 64) {
#pragma unroll
    for (int i = 0; i < ACH; i++)
      gl_lds16(A + (size_t)(brow + rs[i]) * lda + k0 + chs[i] * 8,
               As + i * 4096 + t * 16);
#pragma unroll
    for (int i = 0; i < 4; i++)
      gl_lds16(B + (size_t)(bcol + rs[i]) * ldb + k0 + chs[i] * 8,
               Bs + i * 4096 + t * 16);
    __syncthreads();
#pragma unroll
    for (int kk = 0; kk < 2; kk++) {
      bf16x8 af[MR], bfr[4];
#pragma unroll
      for (int m = 0; m < MR; m++) {
        int row = wr * (BM / 2) + m * 16 + c;
        int ch = (kk * 4 + g) ^ (row & 7);
        af[m] = *(const bf16x8*)(As + row * 128 + ch * 16);
      }
#pragma unroll
      for (int n = 0; n < 4; n++) {
        int row = wc * 64 + n * 16 + c;
        int ch = (kk * 4 + g) ^ (row & 7);
        bfr[n] = *(const bf16x8*)(Bs + row * 128 + ch * 16);
      }
      __builtin_amdgcn_s_setprio(1);
#pragma unroll
      for (int m = 0; m < MR; m++)
#pragma unroll
        for (int n = 0; n < 4; n++)
          acc[m][n] = __builtin_amdgcn_mfma_f32_16x16x32_bf16(af[m], bfr[n], acc[m][n], 0, 0, 0);
      __builtin_amdgcn_s_setprio(0);
    }
    __syncthreads();
  }

#pragma unroll
  for (int n = 0; n < 4; n++) {
    int col = bcol + wc * 64 + n * 16 + c;
    const float* bp = col < 1024 ? b0 : (col < 2048 ? b1 : b2);
    float bv = bp[col & 1023];
    float sc = col < 1024 ? qscale : 1.0f;
#pragma unroll
    for (int m = 0; m < MR; m++) {
      int row0 = brow + wr * (BM / 2) + m * 16 + g * 4;
      float v0 = (acc[m][n][0] + bv) * sc;
      float v1 = (acc[m][n][1] + bv) * sc;
      float v2 = (acc[m][n][2] + bv) * sc;
      float v3 = (acc[m][n][3] + bv) * sc;
      if (VFOLD && col >= 2048) {
        int cv = col - 2048;
        int h = cv >> 6, d = cv & 63;
        int bq = row0 >> 11;
        size_t vaddr = ((size_t)((bq * NH + h) * HDIM + d)) * SEQ + (row0 & (SEQ - 1));
        uint2v uu;
        uu[0] = pack2bf(v0, v1);
        uu[1] = pack2bf(v2, v3);
        *(uint2v*)(Vt + vaddr) = uu;
      } else {
        C[(size_t)(row0 + 0) * ldc + col] = (OutT)v0;
        C[(size_t)(row0 + 1) * ldc + col] = (OutT)v1;
        C[(size_t)(row0 + 2) * ldc + col] = (OutT)v2;
        C[(size_t)(row0 + 3) * ldc + col] = (OutT)v3;
      }
    }
  }
}

// ---------------- flash attention ----------------
// OCCUPANCY CONFIG: 4 blocks/CU (32KB LDS, <=128 VGPR via launch_bounds).
// 4 waves/block: wave = (qhalf, kv-parity), 32 q rows per wave (2 groups of
// 16); block = 64 q rows. kv step = pair of 128 rows, parity split.
// K staged in LDS (pair = 16KB, double-buffered = 32KB); V read DIRECTLY from
// global/L2 into registers (Vt layout (B,H,Hd,N) -> 16B/lane, 4 lanes per 64B
// line; per-(b,h) V slice = 256KB, L2-resident, shared by 32 blocks).
// Swapped QK^T with permuted K rows rho(n,s)=(n>>1)*32+(s>>2)*8+(n&1)*4+(s&3):
// softmax output lands directly in PV's B-operand layout. Q pre-scaled by
// 0.125*log2e -> p = exp2(st), pure-additive softmax (no max; parity merge =
// add in LDS). K LDS swizzle sigma(row)=(row&3)|((row&8)>>1) conflict-free.
// V fragment loads issued early (dt0/1 after QK, dt2/3 after pack) so the
// softmax VALU covers their L2 latency.
__global__ __launch_bounds__(256, 4) void attn_fwd(const __bf16* __restrict__ Q,
                                                   const __bf16* __restrict__ Kg,
                                                   const __bf16* __restrict__ Vt,
                                                   __bf16* __restrict__ AO,
                                                   const int* __restrict__ causal_p) {
  __shared__ __align__(16) unsigned char lds[32768];   // 2 x 16KB K-pair buffers
  const int t = threadIdx.x;
  const int lane = t & 63;
  const int w = t >> 6;
  const int c = lane & 15, g = lane >> 4;
  const int qhalf = w >> 1, parity = w & 1;
  const int bh = blockIdx.y;
  const int b = bh >> 4, h = bh & 15;
  const int q0 = blockIdx.x * 64;
  const int causal = causal_p[0];
  const int qbase = q0 + qhalf * 32;   // this wave's 32 q rows

  // Q fragments (pre-scaled): lane holds Q[qbase+u*16+c][kk*32+8g+j]
  bf16x8 qf[2][2];
#pragma unroll
  for (int u = 0; u < 2; u++)
#pragma unroll
    for (int kk = 0; kk < 2; kk++)
      qf[u][kk] = *(const bf16x8*)(Q + (size_t)(b * SEQ + qbase + u * 16 + c) * NQKV +
                                   h * HDIM + kk * 32 + g * 8);

  f32x4 oacc[2][4] = {};
  float lrun[2] = {0.f, 0.f};

  // staging tables: K pair = 128 rows x 128B, 4 chunks of 4KB
  int srow[4], schk[4];
#pragma unroll
  for (int i = 0; i < 4; i++) {
    int lb = i * 4096 + t * 16;
    int row = lb >> 7, ch = (lb & 127) >> 4;
    int sig = (row & 3) | ((row & 8) >> 1);
    srow[i] = row; schk[i] = ch ^ sig;
  }

  // hoisted K LDS read offsets (parity selects 8KB half of the pair)
  int voffK[8];
#pragma unroll
  for (int n = 0; n < 4; n++) {
    int row = ((n >> 1) << 5) + ((c >> 2) << 3) + ((n & 1) << 2) + (c & 3);
    int sig = (row & 3) | ((row & 8) >> 1);
#pragma unroll
    for (int kk = 0; kk < 2; kk++)
      voffK[n * 2 + kk] = parity * 8192 + row * 128 + (((kk * 4 + g) ^ sig) << 4);
  }

  const __bf16* Kbase = Kg + (size_t)b * SEQ * NQKV + h * HDIM;
  // per-lane V base for fragment rows: row d = dt*16 + c, col k along N
  const __bf16* Vlane = Vt + (size_t)bh * HDIM * SEQ + (size_t)c * SEQ + g * 8;

  const int kvend = causal ? (q0 + 64 < SEQ ? q0 + 64 : SEQ) : SEQ;
  const int nstep = (kvend + 127) >> 7;

#define STAGE_K(JP, PB)                                                             \
  do {                                                                              \
    _Pragma("unroll")                                                               \
    for (int i = 0; i < 4; i++)                                                     \
      gl_lds16(Kbase + (size_t)(((JP) << 7) + srow[i]) * NQKV + schk[i] * 8,        \
               lds + (PB) + i * 4096 + t * 16);                                     \
  } while (0)

#define ATTN_STEP(JV, BOFS, PBNEXT)                                                 \
  do {                                                                              \
    if ((JV) + 1 < nstep) STAGE_K((JV) + 1, PBNEXT);                                \
    const int kvp = ((JV) << 7) + parity * 64;                                      \
    f32x4 st[2][4] = {};                                                            \
    __builtin_amdgcn_s_setprio(1);                                                  \
    _Pragma("unroll")                                                               \
    for (int n = 0; n < 4; n++) {                                                   \
      _Pragma("unroll")                                                             \
      for (int kk = 0; kk < 2; kk++) {                                              \
        bf16x8 kf = *(const bf16x8*)(lds + (BOFS) + voffK[n * 2 + kk]);             \
        st[0][n] = __builtin_amdgcn_mfma_f32_16x16x32_bf16(kf, qf[0][kk], st[0][n], 0, 0, 0); \
        st[1][n] = __builtin_amdgcn_mfma_f32_16x16x32_bf16(kf, qf[1][kk], st[1][n], 0, 0, 0); \
      }                                                                             \
    }                                                                               \
    __builtin_amdgcn_s_setprio(0);                                                  \
    /* V fragments dt 0,1 -- softmax below covers their L2 latency */               \
    bf16x8 vf01[4];                                                                 \
    _Pragma("unroll")                                                               \
    for (int dt = 0; dt < 2; dt++)                                                  \
      _Pragma("unroll")                                                             \
      for (int kk2 = 0; kk2 < 2; kk2++)                                             \
        vf01[dt * 2 + kk2] = *(const bf16x8*)(Vlane + (size_t)(dt * 16) * SEQ + kvp + kk2 * 32); \
    if (causal) {                                                                   \
      _Pragma("unroll")                                                             \
      for (int u = 0; u < 2; u++) {                                                 \
        const int qrow_u = qbase + u * 16 + c;                                      \
        _Pragma("unroll")                                                           \
        for (int n = 0; n < 4; n++) {                                               \
          _Pragma("unroll")                                                         \
          for (int r = 0; r < 4; r++) {                                             \
            int kabs = kvp + ((n >> 1) << 5) + (g << 3) + ((n & 1) << 2) + r;       \
            if (kabs > qrow_u) st[u][n][r] = -3.0e38f;                              \
          }                                                                         \
        }                                                                           \
      }                                                                             \
    }                                                                               \
    bf16x8 pfr[2][2];                                                               \
    _Pragma("unroll")                                                               \
    for (int u = 0; u < 2; u++) {                                                   \
      _Pragma("unroll")                                                             \
      for (int n = 0; n < 4; n++) {                                                 \
        st[u][n][0] = EXP2F(st[u][n][0]);                                           \
        st[u][n][1] = EXP2F(st[u][n][1]);                                           \
        st[u][n][2] = EXP2F(st[u][n][2]);                                           \
        st[u][n][3] = EXP2F(st[u][n][3]);                                           \
      }                                                                             \
      float ps0 = (st[u][0][0] + st[u][0][1]) + (st[u][0][2] + st[u][0][3]);        \
      float ps1 = (st[u][1][0] + st[u][1][1]) + (st[u][1][2] + st[u][1][3]);        \
      float ps2 = (st[u][2][0] + st[u][2][1]) + (st[u][2][2] + st[u][2][3]);        \
      float ps3 = (st[u][3][0] + st[u][3][1]) + (st[u][3][2] + st[u][3][3]);        \
      lrun[u] += (ps0 + ps1) + (ps2 + ps3);                                         \
      _Pragma("unroll")                                                             \
      for (int kk2 = 0; kk2 < 2; kk2++) {                                           \
        int n0i = 2 * kk2, n1i = 2 * kk2 + 1;                                       \
        uint4v uu4;                                                                 \
        uu4[0] = pack2bf(st[u][n0i][0], st[u][n0i][1]);                             \
        uu4[1] = pack2bf(st[u][n0i][2], st[u][n0i][3]);                             \
        uu4[2] = pack2bf(st[u][n1i][0], st[u][n1i][1]);                             \
        uu4[3] = pack2bf(st[u][n1i][2], st[u][n1i][3]);                             \
        pfr[u][kk2] = __builtin_bit_cast(bf16x8, uu4);                              \
      }                                                                             \
    }                                                                               \
    bf16x8 vf23[4];                                                                 \
    _Pragma("unroll")                                                               \
    for (int dt = 0; dt < 2; dt++)                                                  \
      _Pragma("unroll")                                                             \
      for (int kk2 = 0; kk2 < 2; kk2++)                                             \
        vf23[dt * 2 + kk2] = *(const bf16x8*)(Vlane + (size_t)((dt + 2) * 16) * SEQ + kvp + kk2 * 32); \
    __builtin_amdgcn_s_setprio(1);                                                  \
    _Pragma("unroll")                                                               \
    for (int dt = 0; dt < 2; dt++)                                                  \
      _Pragma("unroll")                                                             \
      for (int kk2 = 0; kk2 < 2; kk2++) {                                           \
        oacc[0][dt] = __builtin_amdgcn_mfma_f32_16x16x32_bf16(                      \
            vf01[dt * 2 + kk2], pfr[0][kk2], oacc[0][dt], 0, 0, 0);                 \
        oacc[1][dt] = __builtin_amdgcn_mfma_f32_16x16x32_bf16(                      \
            vf01[dt * 2 + kk2], pfr[1][kk2], oacc[1][dt], 0, 0, 0);                 \
      }                                                                             \
    _Pragma("unroll")                                                               \
    for (int dt = 0; dt < 2; dt++)                                                  \
      _Pragma("unroll")                                                             \
      for (int kk2 = 0; kk2 < 2; kk2++) {                                           \
        oacc[0][dt + 2] = __builtin_amdgcn_mfma_f32_16x16x32_bf16(                  \
            vf23[dt * 2 + kk2], pfr[0][kk2], oacc[0][dt + 2], 0, 0, 0);             \
        oacc[1][dt + 2] = __builtin_amdgcn_mfma_f32_16x16x32_bf16(                  \
            vf23[dt * 2 + kk2], pfr[1][kk2], oacc[1][dt + 2], 0, 0, 0);             \
      }                                                                             \
    __builtin_amdgcn_s_setprio(0);                                                  \
    __syncthreads();                                                                \
  } while (0)

  // prologue: stage pair 0 into buffer 0
  STAGE_K(0, 0);
  __syncthreads();

  for (int j = 0; j < nstep; j += 2) {
    ATTN_STEP(j, 0, 16384);
    if (j + 1 < nstep) ATTN_STEP(j + 1, 16384, 0);
  }

  // ---- parity merge via LDS (pure-additive softmax => simple add) ----
  // mf padded to stride 65 words to break the d-major bank alias.
  float* mf = (float*)lds;                 // [64 d][65] f32 (16.6KB)
  float* ml = (float*)(lds + 16640);       // 64 l values
  if (parity == 1) {
#pragma unroll
    for (int u = 0; u < 2; u++) {
      const int qi = qhalf * 32 + u * 16 + c;
#pragma unroll
      for (int dt = 0; dt < 4; dt++) {
#pragma unroll
        for (int r = 0; r < 4; r++) {
          int d = dt * 16 + 4 * g + r;
          mf[d * 65 + qi] = oacc[u][dt][r];
        }
      }
      float l = lrun[u];
      l += __shfl_xor(l, 16);
      l += __shfl_xor(l, 32);
      ml[qi] = l;
    }
  }
  __syncthreads();
  if (parity == 0) {
#pragma unroll
    for (int u = 0; u < 2; u++) {
      const int qi = qhalf * 32 + u * 16 + c;
      float l = lrun[u];
      l += __shfl_xor(l, 16);
      l += __shfl_xor(l, 32);
      l += ml[qi];
      float inv = 1.0f / l;
      const int qrow_u = qbase + u * 16 + c;
#pragma unroll
      for (int dt = 0; dt < 4; dt++) {
        f32x4 o;
#pragma unroll
        for (int r = 0; r < 4; r++) {
          int d = dt * 16 + 4 * g + r;
          o[r] = (oacc[u][dt][r] + mf[d * 65 + qi]) * inv;
        }
        uint2v uu;
        uu[0] = pack2bf(o[0], o[1]);
        uu[1] = pack2bf(o[2], o[3]);
        *(uint2v*)(AO + (size_t)(b * SEQ + qrow_u) * NQKV + h * HDIM + dt * 16 + g * 4) = uu;
      }
    }
  }
#undef STAGE_K
#undef ATTN_STEP
}

// ---------------- launch ----------------
extern "C" void kernel_launch(void* const* d_in, const int* in_sizes, int n_in,
                              void* d_out, int out_size, void* d_ws, size_t ws_size,
                              hipStream_t stream) {
  const float* x  = (const float*)d_in[0];
  const float* Wq = (const float*)d_in[1];
  const float* bq = (const float*)d_in[2];
  const float* Wk = (const float*)d_in[3];
  const float* bk = (const float*)d_in[4];
  const float* Wv = (const float*)d_in[5];
  const float* bv = (const float*)d_in[6];
  const float* Wo = (const float*)d_in[7];
  const float* bo = (const float*)d_in[8];
  const int* causal = (const int*)d_in[9];
  float* out = (float*)d_out;

  char* ws = (char*)d_ws;
  const size_t SZ_TOK = (size_t)MTOK * D_EMB * sizeof(__bf16);   // 8 MiB
  const size_t SZ_W   = (size_t)D_EMB * D_EMB * sizeof(__bf16);  // 2 MiB
  __bf16* xb   = (__bf16*)(ws);                       // 8 MiB
  __bf16* Wob  = (__bf16*)(ws + SZ_TOK);              // 2 MiB
  __bf16* Wcat = (__bf16*)(ws + SZ_TOK + SZ_W);       // 6 MiB [Wq;Wk;Wv]
  __bf16* QKV  = (__bf16*)(ws + SZ_TOK + 4 * SZ_W);   // 24 MiB, row stride 3072
  __bf16* Vtb  = (__bf16*)(ws + 4 * SZ_TOK + 4 * SZ_W);  // 8 MiB (B,H,Hd,N)
  __bf16* Qb   = QKV;
  __bf16* Kb   = QKV + D_EMB;
  __bf16* AOb  = QKV + 2 * D_EMB;   // V columns unused (folded to Vt) -> reuse for AO

  cast_all<<<4096, 256, 0, stream>>>(x, Wq, Wk, Wv, Wo, xb, Wcat, Wob);

  // fused QKV projection (128x128): Q,K -> QKV cols [0,2048); V -> Vtb
  gemm_bt<__bf16, 128, true><<<dim3(NQKV / 128, MTOK / 128), 256, 0, stream>>>(
      xb, Wcat, bq, bk, bv, CSCALE, QKV, Vtb, D_EMB, D_EMB, D_EMB, NQKV);

  attn_fwd<<<dim3(SEQ / 64, BATCH * NH), 256, 0, stream>>>(Qb, Kb, Vtb, AOb, causal);

  // output projection: out(4096,1024) = AO * Wo^T + bo  (BM=64 -> 512 blocks)
  gemm_bt<float, 64, false><<<dim3(D_EMB / 128, MTOK / 64), 256, 0, stream>>>(
      AOb, Wob, bo, bo, bo, 1.0f, out, nullptr, D_EMB, NQKV, D_EMB, D_EMB);
}

// Round 10
// 111.185 us; speedup vs baseline: 1.5958x; 1.5958x over previous
//
#include <hip/hip_runtime.h>
#include <hip/hip_bf16.h>
#include <cstdint>
#include <cstddef>

#define DEVI __device__ __forceinline__

typedef __attribute__((ext_vector_type(8))) __bf16 bf16x8;
typedef __attribute__((ext_vector_type(4))) float  f32x4;
typedef __attribute__((ext_vector_type(4))) unsigned int uint4v;
typedef __attribute__((ext_vector_type(2))) unsigned int uint2v;

static constexpr int D_EMB = 1024;
static constexpr int NH    = 16;
static constexpr int HDIM  = 64;
static constexpr int BATCH = 2;
static constexpr int SEQ   = 2048;
static constexpr int MTOK  = BATCH * SEQ;    // 4096
static constexpr int NQKV  = 3 * D_EMB;      // 3072
static constexpr float L2E = 1.44269504088896340736f;
static constexpr float CSCALE = 0.125f * L2E;   // 1/sqrt(64) * log2(e), folded into Q

#if __has_builtin(__builtin_amdgcn_exp2f)
#define EXP2F(x) __builtin_amdgcn_exp2f(x)
#else
#define EXP2F(x) exp2f(x)
#endif

typedef __attribute__((address_space(1))) unsigned int* gas_u32;
typedef __attribute__((address_space(3))) unsigned int* las_u32;

// async global->LDS, 16B per lane; dest must be linear (wave base + lane*16)
DEVI void gl_lds16(const void* g, void* l) {
  __builtin_amdgcn_global_load_lds((gas_u32)(void*)g, (las_u32)l, 16, 0, 0);
}

DEVI unsigned pack2bf(float lo, float hi) {
  unsigned short a = __builtin_bit_cast(unsigned short, (__bf16)lo);
  unsigned short b = __builtin_bit_cast(unsigned short, (__bf16)hi);
  return (unsigned)a | ((unsigned)b << 16);
}

// ---------------- fused cast: x + all 4 weights in ONE launch ----------------
__global__ __launch_bounds__(256) void cast_all(const float* __restrict__ x,
                                                const float* __restrict__ Wq,
                                                const float* __restrict__ Wk,
                                                const float* __restrict__ Wv,
                                                const float* __restrict__ Wo,
                                                __bf16* __restrict__ xb,
                                                __bf16* __restrict__ Wcat,
                                                __bf16* __restrict__ Wob) {
  const int bid = blockIdx.x;
  const float* src;
  __bf16* dst;
  size_t off;
  if (bid < 2048)      { src = x;  dst = xb;   off = (size_t)bid * 2048; }
  else if (bid < 2560) { src = Wq; dst = Wcat; off = (size_t)(bid - 2048) * 2048; }
  else if (bid < 3072) { src = Wk; dst = Wcat + (1u << 20); off = (size_t)(bid - 2560) * 2048; }
  else if (bid < 3584) { src = Wv; dst = Wcat + (2u << 20); off = (size_t)(bid - 3072) * 2048; }
  else                 { src = Wo; dst = Wob;  off = (size_t)(bid - 3584) * 2048; }
  size_t i = off + (size_t)threadIdx.x * 8;
  const f32x4* p = (const f32x4*)(src + i);
  f32x4 a = p[0], b = p[1];
  bf16x8 o;
  o[0] = (__bf16)a[0]; o[1] = (__bf16)a[1]; o[2] = (__bf16)a[2]; o[3] = (__bf16)a[3];
  o[4] = (__bf16)b[0]; o[5] = (__bf16)b[1]; o[6] = (__bf16)b[2]; o[7] = (__bf16)b[3];
  *(bf16x8*)(dst + i) = o;
}

// ---------------- GEMM: C(M,N) = A(M,K) * B(N,K)^T + bias ----------------
// R5-proven structure: tile BMx128, BK=64, 256 threads (4 waves 2x2), wave
// tile (BM/2)x64. LDS [row][64] bf16 (128B rows), XOR swizzle chunk^=row&7.
// bias select: col<1024->b0,<2048->b1,else b2. qscale multiplies cols<1024.
// VFOLD: cols >= 2048 (V projection) written TRANSPOSED into Vt(B,H,Hd,N).
template <typename OutT, int BM, bool VFOLD>
__global__ __launch_bounds__(256) void gemm_bt(const __bf16* __restrict__ A,
                                               const __bf16* __restrict__ B,
                                               const float* __restrict__ b0,
                                               const float* __restrict__ b1,
                                               const float* __restrict__ b2,
                                               float qscale,
                                               OutT* __restrict__ C,
                                               __bf16* __restrict__ Vt,
                                               int K, int lda, int ldb, int ldc) {
  constexpr int ACH = BM / 32;
  constexpr int MR  = BM / 32;
  __shared__ __align__(16) unsigned char lds[BM * 128 + 16384];
  unsigned char* As = lds;
  unsigned char* Bs = lds + BM * 128;
  const int t = threadIdx.x;
  const int lane = t & 63;
  const int w = t >> 6;
  const int c = lane & 15, g = lane >> 4;
  const int wr = w >> 1, wc = w & 1;
  const int brow = blockIdx.y * BM;
  const int bcol = blockIdx.x * 128;

  f32x4 acc[MR][4] = {};

  int rs[4], chs[4];
#pragma unroll
  for (int i = 0; i < 4; i++) {
    int lb = i * 4096 + t * 16;
    int row = lb >> 7, ch = (lb & 127) >> 4;
    rs[i] = row; chs[i] = ch ^ (row & 7);
  }

  for (int k0 = 0; k0 < K; k0 += 64) {
#pragma unroll
    for (int i = 0; i < ACH; i++)
      gl_lds16(A + (size_t)(brow + rs[i]) * lda + k0 + chs[i] * 8,
               As + i * 4096 + t * 16);
#pragma unroll
    for (int i = 0; i < 4; i++)
      gl_lds16(B + (size_t)(bcol + rs[i]) * ldb + k0 + chs[i] * 8,
               Bs + i * 4096 + t * 16);
    __syncthreads();
#pragma unroll
    for (int kk = 0; kk < 2; kk++) {
      bf16x8 af[MR], bfr[4];
#pragma unroll
      for (int m = 0; m < MR; m++) {
        int row = wr * (BM / 2) + m * 16 + c;
        int ch = (kk * 4 + g) ^ (row & 7);
        af[m] = *(const bf16x8*)(As + row * 128 + ch * 16);
      }
#pragma unroll
      for (int n = 0; n < 4; n++) {
        int row = wc * 64 + n * 16 + c;
        int ch = (kk * 4 + g) ^ (row & 7);
        bfr[n] = *(const bf16x8*)(Bs + row * 128 + ch * 16);
      }
      __builtin_amdgcn_s_setprio(1);
#pragma unroll
      for (int m = 0; m < MR; m++)
#pragma unroll
        for (int n = 0; n < 4; n++)
          acc[m][n] = __builtin_amdgcn_mfma_f32_16x16x32_bf16(af[m], bfr[n], acc[m][n], 0, 0, 0);
      __builtin_amdgcn_s_setprio(0);
    }
    __syncthreads();
  }

#pragma unroll
  for (int n = 0; n < 4; n++) {
    int col = bcol + wc * 64 + n * 16 + c;
    const float* bp = col < 1024 ? b0 : (col < 2048 ? b1 : b2);
    float bv = bp[col & 1023];
    float sc = col < 1024 ? qscale : 1.0f;
#pragma unroll
    for (int m = 0; m < MR; m++) {
      int row0 = brow + wr * (BM / 2) + m * 16 + g * 4;
      float v0 = (acc[m][n][0] + bv) * sc;
      float v1 = (acc[m][n][1] + bv) * sc;
      float v2 = (acc[m][n][2] + bv) * sc;
      float v3 = (acc[m][n][3] + bv) * sc;
      if (VFOLD && col >= 2048) {
        int cv = col - 2048;
        int h = cv >> 6, d = cv & 63;
        int bq = row0 >> 11;
        size_t vaddr = ((size_t)((bq * NH + h) * HDIM + d)) * SEQ + (row0 & (SEQ - 1));
        uint2v uu;
        uu[0] = pack2bf(v0, v1);
        uu[1] = pack2bf(v2, v3);
        *(uint2v*)(Vt + vaddr) = uu;
      } else {
        C[(size_t)(row0 + 0) * ldc + col] = (OutT)v0;
        C[(size_t)(row0 + 1) * ldc + col] = (OutT)v1;
        C[(size_t)(row0 + 2) * ldc + col] = (OutT)v2;
        C[(size_t)(row0 + 3) * ldc + col] = (OutT)v3;
      }
    }
  }
}

// ---------------- flash attention ----------------
// 8 waves/block (512 thr): wave = (qhalf 0..3, kv-parity), 32 q rows per wave,
// block = 128 q rows. KV pairs (128 rows) staged into 32KB buffers, double-
// buffered (64KB LDS) -> 2 blocks/CU x 8 waves = 4 waves/SIMD (2x the latency
// hiding of the 4-wave version at identical per-wave dataflow).
// Swapped QK^T with permuted K rows rho(n,s)=(n>>1)*32+(s>>2)*8+(n&1)*4+(s&3):
// softmax output lands directly in PV's B-operand layout (zero shuffles).
// Q pre-scaled by 0.125*log2e -> p = exp2(st); pure-additive softmax (no max
// tracking; parity merge = add in LDS).
// LDS swizzle sigma(row)=(row&3)|((row&8)>>1). Key identity: for the QK read
// rows sigma == c&7 and for PV rows sigma == (c&3)|((c&8)>>1) -- both
// independent of n/dt, so read offsets = ONE base register per kk plus
// compile-time offsets (saves ~12 VGPR; fits 128-reg cap of (512,2) unspilled).
__global__ __launch_bounds__(512, 2) void attn_fwd(const __bf16* __restrict__ Q,
                                                   const __bf16* __restrict__ Kg,
                                                   const __bf16* __restrict__ Vt,
                                                   __bf16* __restrict__ AO,
                                                   const int* __restrict__ causal_p) {
  __shared__ __align__(16) unsigned char lds[65536];   // 2 pair-buffers x 32KB
  const int t = threadIdx.x;
  const int lane = t & 63;
  const int w = t >> 6;                  // 0..7
  const int c = lane & 15, g = lane >> 4;
  const int qhalf = w >> 1, parity = w & 1;
  const int bh = blockIdx.y;
  const int b = bh >> 4, h = bh & 15;
  const int q0 = blockIdx.x * 128;
  const int causal = causal_p[0];
  const int qbase = q0 + qhalf * 32;     // this wave's 32 q rows

  // Q fragments (pre-scaled): lane holds Q[qbase+u*16+c][kk*32+8g+j]
  bf16x8 qf[2][2];
#pragma unroll
  for (int u = 0; u < 2; u++)
#pragma unroll
    for (int kk = 0; kk < 2; kk++)
      qf[u][kk] = *(const bf16x8*)(Q + (size_t)(b * SEQ + qbase + u * 16 + c) * NQKV +
                                   h * HDIM + kk * 32 + g * 8);

  f32x4 oacc[2][4] = {};
  float lrun[2] = {0.f, 0.f};

  // staging scalars: 512 threads x 16B = one 8KB quarter per issue
  const int slb = t * 16;
  const int srow = slb >> 7;             // 0..63
  const int ssig = (srow & 3) | ((srow & 8) >> 1);
  const int schk = (((slb & 127) >> 4) ^ ssig);

  // hoisted LDS read bases (quarters: [Ke 8K][Ve 8K][Ko 8K][Vo 8K] per buffer)
  int kb[2], vb[2];
  {
    const int sigK = c & 7;
    const int sigV = (c & 3) | ((c & 8) >> 1);
    const int crow = ((c >> 2) * 8 + (c & 3)) * 128;
#pragma unroll
    for (int kk = 0; kk < 2; kk++) {
      kb[kk] = parity * 16384 + crow + ((((kk * 4 + g) ^ sigK)) << 4);
      vb[kk] = parity * 16384 + 8192 + c * 128 + ((((kk * 4 + g) ^ sigV)) << 4);
    }
  }

  const __bf16* Kbase = Kg + (size_t)b * SEQ * NQKV + h * HDIM;
  const __bf16* Vbase = Vt + (size_t)bh * HDIM * SEQ;

  const int kvend = causal ? (q0 + 128 < SEQ ? q0 + 128 : SEQ) : SEQ;
  const int npair = kvend >> 7;

#define STAGE_PAIR(JP, PB)                                                          \
  do {                                                                              \
    int kvn = (JP) << 7;                                                            \
    gl_lds16(Kbase + (size_t)(kvn + srow) * NQKV + schk * 8,      lds + (PB) + t * 16);          \
    gl_lds16(Vbase + (size_t)srow * SEQ + kvn + schk * 8,         lds + (PB) + 8192 + t * 16);   \
    gl_lds16(Kbase + (size_t)(kvn + 64 + srow) * NQKV + schk * 8, lds + (PB) + 16384 + t * 16);  \
    gl_lds16(Vbase + (size_t)srow * SEQ + kvn + 64 + schk * 8,    lds + (PB) + 24576 + t * 16);  \
  } while (0)

#define ATTN_STEP(JV, BOFS, PBNEXT)                                                 \
  do {                                                                              \
    if ((JV) + 1 < npair) STAGE_PAIR((JV) + 1, PBNEXT);                             \
    f32x4 st[2][4] = {};                                                            \
    __builtin_amdgcn_s_setprio(1);                                                  \
    _Pragma("unroll")                                                               \
    for (int n = 0; n < 4; n++) {                                                   \
      _Pragma("unroll")                                                             \
      for (int kk = 0; kk < 2; kk++) {                                              \
        bf16x8 kf = *(const bf16x8*)(lds + (BOFS) + kb[kk] +                        \
                                     (n >> 1) * 4096 + (n & 1) * 512);              \
        st[0][n] = __builtin_amdgcn_mfma_f32_16x16x32_bf16(kf, qf[0][kk], st[0][n], 0, 0, 0); \
        st[1][n] = __builtin_amdgcn_mfma_f32_16x16x32_bf16(kf, qf[1][kk], st[1][n], 0, 0, 0); \
      }                                                                             \
    }                                                                               \
    __builtin_amdgcn_s_setprio(0);                                                  \
    if (causal) {                                                                   \
      const int kv0 = ((JV) << 7) + parity * 64;                                    \
      _Pragma("unroll")                                                             \
      for (int u = 0; u < 2; u++) {                                                 \
        const int qrow_u = qbase + u * 16 + c;                                      \
        _Pragma("unroll")                                                           \
        for (int n = 0; n < 4; n++) {                                               \
          _Pragma("unroll")                                                         \
          for (int r = 0; r < 4; r++) {                                             \
            int kabs = kv0 + ((n >> 1) << 5) + (g << 3) + ((n & 1) << 2) + r;       \
            if (kabs > qrow_u) st[u][n][r] = -3.0e38f;                              \
          }                                                                         \
        }                                                                           \
      }                                                                             \
    }                                                                               \
    bf16x8 pfr[2][2];                                                               \
    _Pragma("unroll")                                                               \
    for (int u = 0; u < 2; u++) {                                                   \
      _Pragma("unroll")                                                             \
      for (int n = 0; n < 4; n++) {                                                 \
        st[u][n][0] = EXP2F(st[u][n][0]);                                           \
        st[u][n][1] = EXP2F(st[u][n][1]);                                           \
        st[u][n][2] = EXP2F(st[u][n][2]);                                           \
        st[u][n][3] = EXP2F(st[u][n][3]);                                           \
      }                                                                             \
      float ps0 = (st[u][0][0] + st[u][0][1]) + (st[u][0][2] + st[u][0][3]);        \
      float ps1 = (st[u][1][0] + st[u][1][1]) + (st[u][1][2] + st[u][1][3]);        \
      float ps2 = (st[u][2][0] + st[u][2][1]) + (st[u][2][2] + st[u][2][3]);        \
      float ps3 = (st[u][3][0] + st[u][3][1]) + (st[u][3][2] + st[u][3][3]);        \
      lrun[u] += (ps0 + ps1) + (ps2 + ps3);                                         \
      _Pragma("unroll")                                                             \
      for (int kk2 = 0; kk2 < 2; kk2++) {                                           \
        int n0i = 2 * kk2, n1i = 2 * kk2 + 1;                                       \
        uint4v uu4;                                                                 \
        uu4[0] = pack2bf(st[u][n0i][0], st[u][n0i][1]);                             \
        uu4[1] = pack2bf(st[u][n0i][2], st[u][n0i][3]);                             \
        uu4[2] = pack2bf(st[u][n1i][0], st[u][n1i][1]);                             \
        uu4[3] = pack2bf(st[u][n1i][2], st[u][n1i][3]);                             \
        pfr[u][kk2] = __builtin_bit_cast(bf16x8, uu4);                              \
      }                                                                             \
    }                                                                               \
    __builtin_amdgcn_s_setprio(1);                                                  \
    _Pragma("unroll")                                                               \
    for (int dt = 0; dt < 4; dt++) {                                                \
      _Pragma("unroll")                                                             \
      for (int kk2 = 0; kk2 < 2; kk2++) {                                           \
        bf16x8 vf = *(const bf16x8*)(lds + (BOFS) + vb[kk2] + dt * 2048);           \
        oacc[0][dt] = __builtin_amdgcn_mfma_f32_16x16x32_bf16(vf, pfr[0][kk2], oacc[0][dt], 0, 0, 0); \
        oacc[1][dt] = __builtin_amdgcn_mfma_f32_16x16x32_bf16(vf, pfr[1][kk2], oacc[1][dt], 0, 0, 0); \
      }                                                                             \
    }                                                                               \
    __builtin_amdgcn_s_setprio(0);                                                  \
    __syncthreads();                                                                \
  } while (0)

  // prologue: stage pair 0 into buffer 0
  STAGE_PAIR(0, 0);
  __syncthreads();

  for (int j = 0; j < npair; j += 2) {
    ATTN_STEP(j, 0, 32768);
    if (j + 1 < npair) ATTN_STEP(j + 1, 32768, 0);
  }

  // ---- parity merge via LDS (pure-additive softmax => simple add) ----
  // per-qhalf region: [64 d][33] f32 (8448B); l values after all 4 regions.
  float* mf = (float*)(lds + qhalf * 8448);
  float* ml = (float*)(lds + 33792) + qhalf * 32;
  if (parity == 1) {
#pragma unroll
    for (int u = 0; u < 2; u++) {
      const int qi = u * 16 + c;
#pragma unroll
      for (int dt = 0; dt < 4; dt++) {
#pragma unroll
        for (int r = 0; r < 4; r++) {
          int d = dt * 16 + 4 * g + r;
          mf[d * 33 + qi] = oacc[u][dt][r];
        }
      }
      float l = lrun[u];
      l += __shfl_xor(l, 16);
      l += __shfl_xor(l, 32);
      ml[qi] = l;
    }
  }
  __syncthreads();
  if (parity == 0) {
#pragma unroll
    for (int u = 0; u < 2; u++) {
      const int qi = u * 16 + c;
      float l = lrun[u];
      l += __shfl_xor(l, 16);
      l += __shfl_xor(l, 32);
      l += ml[qi];
      float inv = 1.0f / l;
      const int qrow_u = qbase + u * 16 + c;
#pragma unroll
      for (int dt = 0; dt < 4; dt++) {
        f32x4 o;
#pragma unroll
        for (int r = 0; r < 4; r++) {
          int d = dt * 16 + 4 * g + r;
          o[r] = (oacc[u][dt][r] + mf[d * 33 + qi]) * inv;
        }
        uint2v uu;
        uu[0] = pack2bf(o[0], o[1]);
        uu[1] = pack2bf(o[2], o[3]);
        *(uint2v*)(AO + (size_t)(b * SEQ + qrow_u) * NQKV + h * HDIM + dt * 16 + g * 4) = uu;
      }
    }
  }
#undef STAGE_PAIR
#undef ATTN_STEP
}

// ---------------- launch ----------------
extern "C" void kernel_launch(void* const* d_in, const int* in_sizes, int n_in,
                              void* d_out, int out_size, void* d_ws, size_t ws_size,
                              hipStream_t stream) {
  const float* x  = (const float*)d_in[0];
  const float* Wq = (const float*)d_in[1];
  const float* bq = (const float*)d_in[2];
  const float* Wk = (const float*)d_in[3];
  const float* bk = (const float*)d_in[4];
  const float* Wv = (const float*)d_in[5];
  const float* bv = (const float*)d_in[6];
  const float* Wo = (const float*)d_in[7];
  const float* bo = (const float*)d_in[8];
  const int* causal = (const int*)d_in[9];
  float* out = (float*)d_out;

  char* ws = (char*)d_ws;
  const size_t SZ_TOK = (size_t)MTOK * D_EMB * sizeof(__bf16);   // 8 MiB
  const size_t SZ_W   = (size_t)D_EMB * D_EMB * sizeof(__bf16);  // 2 MiB
  __bf16* xb   = (__bf16*)(ws);                       // 8 MiB
  __bf16* Wob  = (__bf16*)(ws + SZ_TOK);              // 2 MiB
  __bf16* Wcat = (__bf16*)(ws + SZ_TOK + SZ_W);       // 6 MiB [Wq;Wk;Wv]
  __bf16* QKV  = (__bf16*)(ws + SZ_TOK + 4 * SZ_W);   // 24 MiB, row stride 3072
  __bf16* Vtb  = (__bf16*)(ws + 4 * SZ_TOK + 4 * SZ_W);  // 8 MiB (B,H,Hd,N)
  __bf16* Qb   = QKV;
  __bf16* Kb   = QKV + D_EMB;
  __bf16* AOb  = QKV + 2 * D_EMB;   // V columns unused (folded to Vt) -> reuse for AO

  cast_all<<<4096, 256, 0, stream>>>(x, Wq, Wk, Wv, Wo, xb, Wcat, Wob);

  // fused QKV projection (128x128): Q,K -> QKV cols [0,2048); V -> Vtb
  gemm_bt<__bf16, 128, true><<<dim3(NQKV / 128, MTOK / 128), 256, 0, stream>>>(
      xb, Wcat, bq, bk, bv, CSCALE, QKV, Vtb, D_EMB, D_EMB, D_EMB, NQKV);

  attn_fwd<<<dim3(SEQ / 128, BATCH * NH), 512, 0, stream>>>(Qb, Kb, Vtb, AOb, causal);

  // output projection: out(4096,1024) = AO * Wo^T + bo  (BM=64 -> 512 blocks)
  gemm_bt<float, 64, false><<<dim3(D_EMB / 128, MTOK / 64), 256, 0, stream>>>(
      AOb, Wob, bo, bo, bo, 1.0f, out, nullptr, D_EMB, NQKV, D_EMB, D_EMB);
}

// Round 11
// 106.131 us; speedup vs baseline: 1.6718x; 1.0476x over previous
//
#include <hip/hip_runtime.h>
#include <hip/hip_bf16.h>
#include <cstdint>
#include <cstddef>

#define DEVI __device__ __forceinline__

typedef __attribute__((ext_vector_type(8))) __bf16 bf16x8;
typedef __attribute__((ext_vector_type(4))) float  f32x4;
typedef __attribute__((ext_vector_type(4))) unsigned int uint4v;
typedef __attribute__((ext_vector_type(2))) unsigned int uint2v;

static constexpr int D_EMB = 1024;
static constexpr int NH    = 16;
static constexpr int HDIM  = 64;
static constexpr int BATCH = 2;
static constexpr int SEQ   = 2048;
static constexpr int MTOK  = BATCH * SEQ;    // 4096
static constexpr int NQKV  = 3 * D_EMB;      // 3072
static constexpr float L2E = 1.44269504088896340736f;
static constexpr float CSCALE = 0.125f * L2E;   // 1/sqrt(64) * log2(e), folded into Q

#if __has_builtin(__builtin_amdgcn_exp2f)
#define EXP2F(x) __builtin_amdgcn_exp2f(x)
#else
#define EXP2F(x) exp2f(x)
#endif

typedef __attribute__((address_space(1))) unsigned int* gas_u32;
typedef __attribute__((address_space(3))) unsigned int* las_u32;

// async global->LDS, 16B per lane; dest must be linear (wave base + lane*16)
DEVI void gl_lds16(const void* g, void* l) {
  __builtin_amdgcn_global_load_lds((gas_u32)(void*)g, (las_u32)l, 16, 0, 0);
}

DEVI unsigned pack2bf(float lo, float hi) {
  unsigned short a = __builtin_bit_cast(unsigned short, (__bf16)lo);
  unsigned short b = __builtin_bit_cast(unsigned short, (__bf16)hi);
  return (unsigned)a | ((unsigned)b << 16);
}

// ---------------- fused cast: x + all 4 weights in ONE launch ----------------
__global__ __launch_bounds__(256) void cast_all(const float* __restrict__ x,
                                                const float* __restrict__ Wq,
                                                const float* __restrict__ Wk,
                                                const float* __restrict__ Wv,
                                                const float* __restrict__ Wo,
                                                __bf16* __restrict__ xb,
                                                __bf16* __restrict__ Wcat,
                                                __bf16* __restrict__ Wob) {
  const int bid = blockIdx.x;
  const float* src;
  __bf16* dst;
  size_t off;
  if (bid < 2048)      { src = x;  dst = xb;   off = (size_t)bid * 2048; }
  else if (bid < 2560) { src = Wq; dst = Wcat; off = (size_t)(bid - 2048) * 2048; }
  else if (bid < 3072) { src = Wk; dst = Wcat + (1u << 20); off = (size_t)(bid - 2560) * 2048; }
  else if (bid < 3584) { src = Wv; dst = Wcat + (2u << 20); off = (size_t)(bid - 3072) * 2048; }
  else                 { src = Wo; dst = Wob;  off = (size_t)(bid - 3584) * 2048; }
  size_t i = off + (size_t)threadIdx.x * 8;
  const f32x4* p = (const f32x4*)(src + i);
  f32x4 a = p[0], b = p[1];
  bf16x8 o;
  o[0] = (__bf16)a[0]; o[1] = (__bf16)a[1]; o[2] = (__bf16)a[2]; o[3] = (__bf16)a[3];
  o[4] = (__bf16)b[0]; o[5] = (__bf16)b[1]; o[6] = (__bf16)b[2]; o[7] = (__bf16)b[3];
  *(bf16x8*)(dst + i) = o;
}

// ---------------- GEMM: C(M,N) = A(M,K) * B(N,K)^T + bias ----------------
// R5-proven structure: tile BMx128, BK=64, 256 threads (4 waves 2x2), wave
// tile (BM/2)x64. LDS [row][64] bf16 (128B rows), XOR swizzle chunk^=row&7.
// bias select: col<1024->b0,<2048->b1,else b2. qscale multiplies cols<1024.
// VFOLD: cols >= 2048 (V projection) written TRANSPOSED into Vt(B,H,Hd,N).
template <typename OutT, int BM, bool VFOLD>
__global__ __launch_bounds__(256) void gemm_bt(const __bf16* __restrict__ A,
                                               const __bf16* __restrict__ B,
                                               const float* __restrict__ b0,
                                               const float* __restrict__ b1,
                                               const float* __restrict__ b2,
                                               float qscale,
                                               OutT* __restrict__ C,
                                               __bf16* __restrict__ Vt,
                                               int K, int lda, int ldb, int ldc) {
  constexpr int ACH = BM / 32;
  constexpr int MR  = BM / 32;
  __shared__ __align__(16) unsigned char lds[BM * 128 + 16384];
  unsigned char* As = lds;
  unsigned char* Bs = lds + BM * 128;
  const int t = threadIdx.x;
  const int lane = t & 63;
  const int w = t >> 6;
  const int c = lane & 15, g = lane >> 4;
  const int wr = w >> 1, wc = w & 1;
  const int brow = blockIdx.y * BM;
  const int bcol = blockIdx.x * 128;

  f32x4 acc[MR][4] = {};

  int rs[4], chs[4];
#pragma unroll
  for (int i = 0; i < 4; i++) {
    int lb = i * 4096 + t * 16;
    int row = lb >> 7, ch = (lb & 127) >> 4;
    rs[i] = row; chs[i] = ch ^ (row & 7);
  }

  for (int k0 = 0; k0 < K; k0 += 64) {
#pragma unroll
    for (int i = 0; i < ACH; i++)
      gl_lds16(A + (size_t)(brow + rs[i]) * lda + k0 + chs[i] * 8,
               As + i * 4096 + t * 16);
#pragma unroll
    for (int i = 0; i < 4; i++)
      gl_lds16(B + (size_t)(bcol + rs[i]) * ldb + k0 + chs[i] * 8,
               Bs + i * 4096 + t * 16);
    __syncthreads();
#pragma unroll
    for (int kk = 0; kk < 2; kk++) {
      bf16x8 af[MR], bfr[4];
#pragma unroll
      for (int m = 0; m < MR; m++) {
        int row = wr * (BM / 2) + m * 16 + c;
        int ch = (kk * 4 + g) ^ (row & 7);
        af[m] = *(const bf16x8*)(As + row * 128 + ch * 16);
      }
#pragma unroll
      for (int n = 0; n < 4; n++) {
        int row = wc * 64 + n * 16 + c;
        int ch = (kk * 4 + g) ^ (row & 7);
        bfr[n] = *(const bf16x8*)(Bs + row * 128 + ch * 16);
      }
      __builtin_amdgcn_s_setprio(1);
#pragma unroll
      for (int m = 0; m < MR; m++)
#pragma unroll
        for (int n = 0; n < 4; n++)
          acc[m][n] = __builtin_amdgcn_mfma_f32_16x16x32_bf16(af[m], bfr[n], acc[m][n], 0, 0, 0);
      __builtin_amdgcn_s_setprio(0);
    }
    __syncthreads();
  }

#pragma unroll
  for (int n = 0; n < 4; n++) {
    int col = bcol + wc * 64 + n * 16 + c;
    const float* bp = col < 1024 ? b0 : (col < 2048 ? b1 : b2);
    float bv = bp[col & 1023];
    float sc = col < 1024 ? qscale : 1.0f;
#pragma unroll
    for (int m = 0; m < MR; m++) {
      int row0 = brow + wr * (BM / 2) + m * 16 + g * 4;
      float v0 = (acc[m][n][0] + bv) * sc;
      float v1 = (acc[m][n][1] + bv) * sc;
      float v2 = (acc[m][n][2] + bv) * sc;
      float v3 = (acc[m][n][3] + bv) * sc;
      if (VFOLD && col >= 2048) {
        int cv = col - 2048;
        int h = cv >> 6, d = cv & 63;
        int bq = row0 >> 11;
        size_t vaddr = ((size_t)((bq * NH + h) * HDIM + d)) * SEQ + (row0 & (SEQ - 1));
        uint2v uu;
        uu[0] = pack2bf(v0, v1);
        uu[1] = pack2bf(v2, v3);
        *(uint2v*)(Vt + vaddr) = uu;
      } else {
        C[(size_t)(row0 + 0) * ldc + col] = (OutT)v0;
        C[(size_t)(row0 + 1) * ldc + col] = (OutT)v1;
        C[(size_t)(row0 + 2) * ldc + col] = (OutT)v2;
        C[(size_t)(row0 + 3) * ldc + col] = (OutT)v3;
      }
    }
  }
}

// ---------------- flash attention (R5-proven config + XCD-locality swizzle) --
// 4 waves/block: wave = (qhalf, kv-parity), 64 q rows per wave (4 groups of
// 16). KV tiles staged in PAIRS (128 rows) into 32KB buffers, double-buffered
// (64KB LDS, 2 blocks/CU). Swapped QK^T with permuted K rows
// rho(n,s)=(n>>1)*32+(s>>2)*8+(n&1)*4+(s&3): softmax output lands directly in
// PV's B-operand layout (zero shuffles). Q pre-scaled by 0.125*log2e ->
// p = exp2(st), pure-additive softmax (no max; parity merge = add in LDS).
// LDS swizzle sigma(row)=(row&3)|((row&8)>>1) conflict-free for both reads.
// XCD SWIZZLE (1-D grid of 512): xcd = fid&7 owns heads [4*xcd, 4*xcd+4) --
// all 16 q-tile blocks of one (b,h) land on ONE XCD, so its 512KB K/V slice
// lives in that XCD's L2 (4 heads x ~1MB = fits 4MB L2) instead of being
// refetched through L3 by all 8 XCDs. Bijective: 512 = 8 * 4heads * 16tiles.
__global__ __launch_bounds__(256, 2) void attn_fwd(const __bf16* __restrict__ Q,
                                                   const __bf16* __restrict__ Kg,
                                                   const __bf16* __restrict__ Vt,
                                                   __bf16* __restrict__ AO,
                                                   const int* __restrict__ causal_p) {
  __shared__ __align__(16) unsigned char lds[65536];   // 2 pair-buffers x 32KB
  const int t = threadIdx.x;
  const int lane = t & 63;
  const int w = t >> 6;
  const int c = lane & 15, g = lane >> 4;
  const int qhalf = w >> 1, parity = w & 1;

  // XCD-locality block swizzle
  const int fid = blockIdx.x;            // 0..511
  const int xcd = fid & 7, j = fid >> 3; // j: 0..63
  const int bh = xcd * 4 + (j >> 4);     // 4 heads per XCD
  const int b = bh >> 4, h = bh & 15;
  const int q0 = (j & 15) * 128;

  const int causal = causal_p[0];
  const int qbase = q0 + qhalf * 64;   // this wave's 64 q rows

  // Q fragments (pre-scaled): lane holds Q[qbase+u*16+c][kk*32+8g+j]
  bf16x8 qf[4][2];
#pragma unroll
  for (int u = 0; u < 4; u++)
#pragma unroll
    for (int kk = 0; kk < 2; kk++)
      qf[u][kk] = *(const bf16x8*)(Q + (size_t)(b * SEQ + qbase + u * 16 + c) * NQKV +
                                   h * HDIM + kk * 32 + g * 8);

  f32x4 oacc[4][4] = {};
  float lrun[4] = {0.f, 0.f, 0.f, 0.f};

  // staging tables (64 rows x 128B per quarter, 2 chunks of 4096B)
  int srow[2], schk[2];
#pragma unroll
  for (int i = 0; i < 2; i++) {
    int lb = i * 4096 + t * 16;
    int row = lb >> 7, ch = (lb & 127) >> 4;
    int sig = (row & 3) | ((row & 8) >> 1);
    srow[i] = row; schk[i] = ch ^ sig;
  }

  // hoisted LDS read offsets (include parity quarter)
  int voffK[8], voffV[8];
#pragma unroll
  for (int n = 0; n < 4; n++) {
    int row = ((n >> 1) << 5) + ((c >> 2) << 3) + ((n & 1) << 2) + (c & 3);
    int sig = (row & 3) | ((row & 8) >> 1);
#pragma unroll
    for (int kk = 0; kk < 2; kk++)
      voffK[n * 2 + kk] = parity * 16384 + row * 128 + (((kk * 4 + g) ^ sig) << 4);
  }
#pragma unroll
  for (int dt = 0; dt < 4; dt++) {
    int row = dt * 16 + c;
    int sig = (row & 3) | ((row & 8) >> 1);
#pragma unroll
    for (int kk2 = 0; kk2 < 2; kk2++)
      voffV[dt * 2 + kk2] = parity * 16384 + 8192 + row * 128 + (((kk2 * 4 + g) ^ sig) << 4);
  }

  const __bf16* Kbase = Kg + (size_t)b * SEQ * NQKV + h * HDIM;
  const __bf16* Vbase = Vt + (size_t)bh * HDIM * SEQ;

  const int kvend = causal ? (q0 + 128 < SEQ ? q0 + 128 : SEQ) : SEQ;
  const int npair = kvend >> 7;

#define STAGE_PAIR(JP, PB)                                                          \
  do {                                                                              \
    int kvn = (JP) << 7;                                                            \
    _Pragma("unroll")                                                               \
    for (int i = 0; i < 2; i++) {                                                   \
      gl_lds16(Kbase + (size_t)(kvn + srow[i]) * NQKV + schk[i] * 8,                \
               lds + (PB) + i * 4096 + t * 16);                                     \
      gl_lds16(Vbase + (size_t)srow[i] * SEQ + kvn + schk[i] * 8,                   \
               lds + (PB) + 8192 + i * 4096 + t * 16);                              \
      gl_lds16(Kbase + (size_t)(kvn + 64 + srow[i]) * NQKV + schk[i] * 8,           \
               lds + (PB) + 16384 + i * 4096 + t * 16);                             \
      gl_lds16(Vbase + (size_t)srow[i] * SEQ + kvn + 64 + schk[i] * 8,              \
               lds + (PB) + 24576 + i * 4096 + t * 16);                             \
    }                                                                               \
  } while (0)

#define ATTN_STEP(JV, BOFS, PBNEXT)                                                 \
  do {                                                                              \
    if ((JV) + 1 < npair) STAGE_PAIR((JV) + 1, PBNEXT);                             \
    f32x4 st[4][4] = {};                                                            \
    __builtin_amdgcn_s_setprio(1);                                                  \
    _Pragma("unroll")                                                               \
    for (int n = 0; n < 4; n++) {                                                   \
      _Pragma("unroll")                                                             \
      for (int kk = 0; kk < 2; kk++) {                                              \
        bf16x8 kf = *(const bf16x8*)(lds + (BOFS) + voffK[n * 2 + kk]);             \
        st[0][n] = __builtin_amdgcn_mfma_f32_16x16x32_bf16(kf, qf[0][kk], st[0][n], 0, 0, 0); \
        st[1][n] = __builtin_amdgcn_mfma_f32_16x16x32_bf16(kf, qf[1][kk], st[1][n], 0, 0, 0); \
        st[2][n] = __builtin_amdgcn_mfma_f32_16x16x32_bf16(kf, qf[2][kk], st[2][n], 0, 0, 0); \
        st[3][n] = __builtin_amdgcn_mfma_f32_16x16x32_bf16(kf, qf[3][kk], st[3][n], 0, 0, 0); \
      }                                                                             \
    }                                                                               \
    __builtin_amdgcn_s_setprio(0);                                                  \
    if (causal) {                                                                   \
      const int kv0 = ((JV) << 7) + parity * 64;                                    \
      _Pragma("unroll")                                                             \
      for (int u = 0; u < 4; u++) {                                                 \
        const int qrow_u = qbase + u * 16 + c;                                      \
        _Pragma("unroll")                                                           \
        for (int n = 0; n < 4; n++) {                                               \
          _Pragma("unroll")                                                         \
          for (int r = 0; r < 4; r++) {                                             \
            int kabs = kv0 + ((n >> 1) << 5) + (g << 3) + ((n & 1) << 2) + r;       \
            if (kabs > qrow_u) st[u][n][r] = -3.0e38f;                              \
          }                                                                         \
        }                                                                           \
      }                                                                             \
    }                                                                               \
    bf16x8 pfrag[4][2];                                                             \
    _Pragma("unroll")                                                               \
    for (int u = 0; u < 4; u++) {                                                   \
      _Pragma("unroll")                                                             \
      for (int n = 0; n < 4; n++) {                                                 \
        st[u][n][0] = EXP2F(st[u][n][0]);                                           \
        st[u][n][1] = EXP2F(st[u][n][1]);                                           \
        st[u][n][2] = EXP2F(st[u][n][2]);                                           \
        st[u][n][3] = EXP2F(st[u][n][3]);                                           \
      }                                                                             \
      float ps0 = (st[u][0][0] + st[u][0][1]) + (st[u][0][2] + st[u][0][3]);        \
      float ps1 = (st[u][1][0] + st[u][1][1]) + (st[u][1][2] + st[u][1][3]);        \
      float ps2 = (st[u][2][0] + st[u][2][1]) + (st[u][2][2] + st[u][2][3]);        \
      float ps3 = (st[u][3][0] + st[u][3][1]) + (st[u][3][2] + st[u][3][3]);        \
      lrun[u] += (ps0 + ps1) + (ps2 + ps3);                                         \
      _Pragma("unroll")                                                             \
      for (int kk2 = 0; kk2 < 2; kk2++) {                                           \
        int n0i = 2 * kk2, n1i = 2 * kk2 + 1;                                       \
        uint4v uu;                                                                  \
        uu[0] = pack2bf(st[u][n0i][0], st[u][n0i][1]);                              \
        uu[1] = pack2bf(st[u][n0i][2], st[u][n0i][3]);                              \
        uu[2] = pack2bf(st[u][n1i][0], st[u][n1i][1]);                              \
        uu[3] = pack2bf(st[u][n1i][2], st[u][n1i][3]);                              \
        pfrag[u][kk2] = __builtin_bit_cast(bf16x8, uu);                             \
      }                                                                             \
    }                                                                               \
    __builtin_amdgcn_s_setprio(1);                                                  \
    _Pragma("unroll")                                                               \
    for (int dt = 0; dt < 4; dt++) {                                                \
      _Pragma("unroll")                                                             \
      for (int kk2 = 0; kk2 < 2; kk2++) {                                           \
        bf16x8 vf = *(const bf16x8*)(lds + (BOFS) + voffV[dt * 2 + kk2]);           \
        oacc[0][dt] = __builtin_amdgcn_mfma_f32_16x16x32_bf16(vf, pfrag[0][kk2], oacc[0][dt], 0, 0, 0); \
        oacc[1][dt] = __builtin_amdgcn_mfma_f32_16x16x32_bf16(vf, pfrag[1][kk2], oacc[1][dt], 0, 0, 0); \
        oacc[2][dt] = __builtin_amdgcn_mfma_f32_16x16x32_bf16(vf, pfrag[2][kk2], oacc[2][dt], 0, 0, 0); \
        oacc[3][dt] = __builtin_amdgcn_mfma_f32_16x16x32_bf16(vf, pfrag[3][kk2], oacc[3][dt], 0, 0, 0); \
      }                                                                             \
    }                                                                               \
    __builtin_amdgcn_s_setprio(0);                                                  \
    __syncthreads();                                                                \
  } while (0)

  // prologue: stage pair 0 into buffer 0
  STAGE_PAIR(0, 0);
  __syncthreads();

  for (int jv = 0; jv < npair; jv += 2) {
    ATTN_STEP(jv, 0, 32768);
    if (jv + 1 < npair) ATTN_STEP(jv + 1, 32768, 0);
  }

  // ---- parity merge via LDS (pure-additive softmax => simple add) ----
  const int mbase = qhalf * 16640;
  float* mf = (float*)(lds + mbase);
  float* ml = (float*)(lds + mbase + 16384);
  if (parity == 1) {
#pragma unroll
    for (int u = 0; u < 4; u++) {
#pragma unroll
      for (int dt = 0; dt < 4; dt++) {
#pragma unroll
        for (int r = 0; r < 4; r++) {
          int d = dt * 16 + 4 * g + r;
          mf[(d << 6) + u * 16 + c] = oacc[u][dt][r];
        }
      }
      float l = lrun[u];
      l += __shfl_xor(l, 16);
      l += __shfl_xor(l, 32);
      ml[u * 16 + c] = l;
    }
  }
  __syncthreads();
  if (parity == 0) {
#pragma unroll
    for (int u = 0; u < 4; u++) {
      float l = lrun[u];
      l += __shfl_xor(l, 16);
      l += __shfl_xor(l, 32);
      l += ml[u * 16 + c];
      float inv = 1.0f / l;
      const int qrow_u = qbase + u * 16 + c;
#pragma unroll
      for (int dt = 0; dt < 4; dt++) {
        f32x4 o;
#pragma unroll
        for (int r = 0; r < 4; r++) {
          int d = dt * 16 + 4 * g + r;
          o[r] = (oacc[u][dt][r] + mf[(d << 6) + u * 16 + c]) * inv;
        }
        uint2v uu;
        uu[0] = pack2bf(o[0], o[1]);
        uu[1] = pack2bf(o[2], o[3]);
        *(uint2v*)(AO + (size_t)(b * SEQ + qrow_u) * NQKV + h * HDIM + dt * 16 + g * 4) = uu;
      }
    }
  }
#undef STAGE_PAIR
#undef ATTN_STEP
}

// ---------------- launch ----------------
extern "C" void kernel_launch(void* const* d_in, const int* in_sizes, int n_in,
                              void* d_out, int out_size, void* d_ws, size_t ws_size,
                              hipStream_t stream) {
  const float* x  = (const float*)d_in[0];
  const float* Wq = (const float*)d_in[1];
  const float* bq = (const float*)d_in[2];
  const float* Wk = (const float*)d_in[3];
  const float* bk = (const float*)d_in[4];
  const float* Wv = (const float*)d_in[5];
  const float* bv = (const float*)d_in[6];
  const float* Wo = (const float*)d_in[7];
  const float* bo = (const float*)d_in[8];
  const int* causal = (const int*)d_in[9];
  float* out = (float*)d_out;

  char* ws = (char*)d_ws;
  const size_t SZ_TOK = (size_t)MTOK * D_EMB * sizeof(__bf16);   // 8 MiB
  const size_t SZ_W   = (size_t)D_EMB * D_EMB * sizeof(__bf16);  // 2 MiB
  __bf16* xb   = (__bf16*)(ws);                       // 8 MiB
  __bf16* Wob  = (__bf16*)(ws + SZ_TOK);              // 2 MiB
  __bf16* Wcat = (__bf16*)(ws + SZ_TOK + SZ_W);       // 6 MiB [Wq;Wk;Wv]
  __bf16* QKV  = (__bf16*)(ws + SZ_TOK + 4 * SZ_W);   // 24 MiB, row stride 3072
  __bf16* Vtb  = (__bf16*)(ws + 4 * SZ_TOK + 4 * SZ_W);  // 8 MiB (B,H,Hd,N)
  __bf16* Qb   = QKV;
  __bf16* Kb   = QKV + D_EMB;
  __bf16* AOb  = QKV + 2 * D_EMB;   // V columns unused (folded to Vt) -> reuse for AO

  cast_all<<<4096, 256, 0, stream>>>(x, Wq, Wk, Wv, Wo, xb, Wcat, Wob);

  // fused QKV projection (128x128): Q,K -> QKV cols [0,2048); V -> Vtb
  gemm_bt<__bf16, 128, true><<<dim3(NQKV / 128, MTOK / 128), 256, 0, stream>>>(
      xb, Wcat, bq, bk, bv, CSCALE, QKV, Vtb, D_EMB, D_EMB, D_EMB, NQKV);

  // attn: 1-D grid, XCD-locality swizzle (512 = 8 XCD x 4 heads x 16 q-tiles)
  attn_fwd<<<dim3(512), 256, 0, stream>>>(Qb, Kb, Vtb, AOb, causal);

  // output projection: out(4096,1024) = AO * Wo^T + bo  (BM=64 -> 512 blocks)
  gemm_bt<float, 64, false><<<dim3(D_EMB / 128, MTOK / 64), 256, 0, stream>>>(
      AOb, Wob, bo, bo, bo, 1.0f, out, nullptr, D_EMB, NQKV, D_EMB, D_EMB);
}